// Round 1
// baseline (288.155 us; speedup 1.0000x reference)
//
#include <hip/hip_runtime.h>
#include <hip/hip_bf16.h>
#include <cstdint>
#include <cstddef>

#define BB 256
#define RR 512
#define AA 196
#define VV 10000
#define MATT (BB*AA)   // 50176
#define NT13 13        // 13*16 = 208 padded attention cols

typedef float f32x4 __attribute__((ext_vector_type(4)));
typedef __bf16 bf16x8 __attribute__((ext_vector_type(8)));

#define MFMA16(a,b,c) __builtin_amdgcn_mfma_f32_16x16x32_bf16(a,b,c,0,0,0)

__device__ __forceinline__ float fast_tanh(float x){
  float ax = fabsf(x);
  float e = __expf(-2.0f*ax);
  float t = (1.0f - e) / (1.0f + e);
  return x < 0.0f ? -t : t;
}

__device__ __forceinline__ bf16x8 ldfrag_f32(const float* p){
  const float4* q = (const float4*)p;
  float4 f0 = q[0];
  float4 f1 = q[1];
  bf16x8 r;
  r[0]=(__bf16)f0.x; r[1]=(__bf16)f0.y; r[2]=(__bf16)f0.z; r[3]=(__bf16)f0.w;
  r[4]=(__bf16)f1.x; r[5]=(__bf16)f1.y; r[6]=(__bf16)f1.z; r[7]=(__bf16)f1.w;
  return r;
}
__device__ __forceinline__ bf16x8 ldfrag_bf(const __bf16* p){
  return *(const bf16x8*)p;
}

// ---------- weight prep ----------
__global__ void cvt_k(const float* __restrict__ src, __bf16* __restrict__ dst, int n){
  int i = blockIdx.x*256 + threadIdx.x;
  if (i < n) dst[i] = (__bf16)src[i];
}

__global__ void wcat_k(const float* __restrict__ Wi2h, const float* __restrict__ Wh2h,
                       const float* __restrict__ Wr2a, __bf16* __restrict__ Wcat){
  int i = blockIdx.x*256 + threadIdx.x;   // < 2048*1536
  int n = i / 1536;
  int k = i - n*1536;
  float v;
  if (k < 512)       v = Wi2h[n*512 + k];
  else if (k < 1024) v = Wh2h[n*512 + (k-512)];
  else               v = Wr2a[n*512 + (k-1024)];
  Wcat[i] = (__bf16)v;
}

__global__ void build_small_k(const float* __restrict__ ba2a, const float* __restrict__ wd2d,
                              const float* __restrict__ bi2h, const float* __restrict__ bh2h,
                              const float* __restrict__ br2a,
                              float* __restrict__ ba_pad, float* __restrict__ wd_pad,
                              float* __restrict__ bcat){
  int i = blockIdx.x*256 + threadIdx.x;
  if (i < 2048){
    bcat[i] = bi2h[i] + bh2h[i] + br2a[i];
  } else if (i < 2048+208){
    int j = i - 2048; ba_pad[j] = (j < AA) ? ba2a[j] : 0.0f;
  } else if (i < 2048+416){
    int j = i - 2256; wd_pad[j] = (j < AA) ? wd2d[j] : 0.0f;
  }
}

// ---------- generic f32-A x bf16-B GEMM:  C[m][n] = sum_k A[m][k]*W[n][k] + bias[n] ----------
// block = 256 threads = 4 waves arranged 2x2, BM=BN=64. M must be multiple of 64.
__global__ __launch_bounds__(256,2) void gemm_bf16_k(
    const float* __restrict__ A, const __bf16* __restrict__ Bw,
    const float* __restrict__ bias, float* __restrict__ C,
    int M, int N, int K)
{
  const int l = threadIdx.x & 63;
  const int w = threadIdx.x >> 6;
  const int l15 = l & 15;
  const int kg = (l >> 4) * 8;
  const int mrow = blockIdx.y*64 + (w>>1)*32;
  const int ncol = blockIdx.x*64 + (w&1)*32;
  int c0 = ncol + l15, c1 = c0 + 16;
  int c0c = c0 < N ? c0 : N-1;
  int c1c = c1 < N ? c1 : N-1;
  const float*  pa0 = A  + (size_t)(mrow + l15)*K + kg;
  const float*  pa1 = pa0 + (size_t)16*K;
  const __bf16* pb0 = Bw + (size_t)c0c*K + kg;
  const __bf16* pb1 = Bw + (size_t)c1c*K + kg;

  f32x4 acc[2][2] = {};
  for (int k = 0; k < K; k += 32){
    bf16x8 a0 = ldfrag_f32(pa0 + k);
    bf16x8 a1 = ldfrag_f32(pa1 + k);
    bf16x8 b0 = ldfrag_bf(pb0 + k);
    bf16x8 b1 = ldfrag_bf(pb1 + k);
    acc[0][0] = MFMA16(a0, b0, acc[0][0]);
    acc[0][1] = MFMA16(a0, b1, acc[0][1]);
    acc[1][0] = MFMA16(a1, b0, acc[1][0]);
    acc[1][1] = MFMA16(a1, b1, acc[1][1]);
  }
  const int rbase = (l >> 4) * 4;
  #pragma unroll
  for (int mt = 0; mt < 2; mt++)
  #pragma unroll
  for (int nt = 0; nt < 2; nt++)
  #pragma unroll
  for (int r = 0; r < 4; r++){
    int row = mrow + mt*16 + rbase + r;
    int col = ncol + nt*16 + l15;
    if (col < N) C[(size_t)row*N + col] = acc[mt][nt][r] + bias[col];
  }
}

// ---------- fused attention score: per wave 32 rows x full 208 cols ----------
// score[l][row] = sum_a tanh( (att@Wa2a^T)[row][a] + ba2a[a] + att_h[l][row] ) * wd2d[a]
__global__ __launch_bounds__(256,1) void att_score_kernel(
    const float* __restrict__ att, const __bf16* __restrict__ Wa2a_bf,
    const float* __restrict__ ba_pad, const float* __restrict__ wd_pad,
    const float* __restrict__ att_h, float* __restrict__ score)
{
  const int l = threadIdx.x & 63;
  const int w = threadIdx.x >> 6;
  const int rowbase = blockIdx.x*128 + w*32;
  const int l15 = l & 15;
  const int kg = (l >> 4) * 8;

  int cc[NT13];
  #pragma unroll
  for (int nt = 0; nt < NT13; nt++){
    int c = nt*16 + l15;
    cc[nt] = c > (AA-1) ? (AA-1) : c;
  }

  const float* pa0 = att + (size_t)(rowbase + l15)*RR + kg;
  const float* pa1 = pa0 + (size_t)16*RR;

  f32x4 acc[2][NT13] = {};
  #pragma unroll 2
  for (int k = 0; k < RR; k += 32){
    bf16x8 a0 = ldfrag_f32(pa0 + k);
    bf16x8 a1 = ldfrag_f32(pa1 + k);
    #pragma unroll
    for (int nt = 0; nt < NT13; nt++){
      bf16x8 b = ldfrag_bf(Wa2a_bf + (size_t)cc[nt]*RR + k + kg);
      acc[0][nt] = MFMA16(a0, b, acc[0][nt]);
      acc[1][nt] = MFMA16(a1, b, acc[1][nt]);
    }
  }

  float wdv[NT13], bav[NT13];
  #pragma unroll
  for (int nt = 0; nt < NT13; nt++){
    int col = nt*16 + l15;
    wdv[nt] = wd_pad[col];
    bav[nt] = ba_pad[col];
  }

  const int rbase = (l >> 4) * 4;
  #pragma unroll
  for (int mt = 0; mt < 2; mt++){
    #pragma unroll
    for (int r = 0; r < 4; r++){
      int row = rowbase + mt*16 + rbase + r;
      float ah0 = att_h[row];
      float ah1 = att_h[MATT + row];
      float s0 = 0.0f, s1 = 0.0f;
      #pragma unroll
      for (int nt = 0; nt < NT13; nt++){
        float v = acc[mt][nt][r] + bav[nt];
        s0 += fast_tanh(v + ah0) * wdv[nt];
        s1 += fast_tanh(v + ah1) * wdv[nt];
      }
      #pragma unroll
      for (int o = 1; o < 16; o <<= 1){
        s0 += __shfl_xor(s0, o, 16);
        s1 += __shfl_xor(s1, o, 16);
      }
      if (l15 == 0){
        score[row] = s0;
        score[MATT + row] = s1;
      }
    }
  }
}

// ---------- softmax over 196 positions, one wave per (layer,b) ----------
__global__ void softmax196_k(const float* __restrict__ score, float* __restrict__ wsm){
  int lb = blockIdx.x;          // l*256 + b
  int t = threadIdx.x;          // 64
  const float* s = score + (size_t)lb*AA;
  float v0 = (t      < AA) ? s[t]       : -3.4e38f;
  float v1 = (t+64   < AA) ? s[t+64]    : -3.4e38f;
  float v2 = (t+128  < AA) ? s[t+128]   : -3.4e38f;
  float v3 = (t+192  < AA) ? s[t+192]   : -3.4e38f;
  float mx = fmaxf(fmaxf(v0,v1), fmaxf(v2,v3));
  #pragma unroll
  for (int o = 1; o < 64; o <<= 1) mx = fmaxf(mx, __shfl_xor(mx, o, 64));
  float e0 = (t      < AA) ? __expf(v0 - mx) : 0.0f;
  float e1 = (t+64   < AA) ? __expf(v1 - mx) : 0.0f;
  float e2 = (t+128  < AA) ? __expf(v2 - mx) : 0.0f;
  float e3 = (t+192  < AA) ? __expf(v3 - mx) : 0.0f;
  float sum = e0+e1+e2+e3;
  #pragma unroll
  for (int o = 1; o < 64; o <<= 1) sum += __shfl_xor(sum, o, 64);
  float inv = 1.0f / sum;
  float* o_ = wsm + (size_t)lb*AA;
  if (t      < AA) o_[t]     = e0*inv;
  if (t+64   < AA) o_[t+64]  = e1*inv;
  if (t+128  < AA) o_[t+128] = e2*inv;
  if (t+192  < AA) o_[t+192] = e3*inv;
}

// ---------- att_res for both layers, writes straight into Xcat slots ----------
__global__ void attres_k(const float* __restrict__ att, const float* __restrict__ wsm,
                         float* __restrict__ Xcat0, float* __restrict__ Xcat1){
  int b = blockIdx.x, t = threadIdx.x;  // 512 threads, t = r
  __shared__ float w0[AA], w1[AA];
  if (t < AA) w0[t] = wsm[(size_t)b*AA + t];
  int t2 = t - 256;
  if (t2 >= 0 && t2 < AA) w1[t2] = wsm[(size_t)(256+b)*AA + t2];
  __syncthreads();
  const float* ap = att + (size_t)b*AA*RR + t;
  float s00=0, s01=0, s10=0, s11=0;
  for (int i = 0; i < AA; i += 2){
    float x0 = ap[(size_t)i*RR];
    float x1 = ap[(size_t)(i+1)*RR];
    s00 += w0[i]*x0;   s10 += w1[i]*x0;
    s01 += w0[i+1]*x1; s11 += w1[i+1]*x1;
  }
  Xcat0[(size_t)b*1536 + 1024 + t] = s00 + s01;
  Xcat1[(size_t)b*1536 + 1024 + t] = s10 + s11;
}

// ---------- fill Xcat cur/prev_h slots ----------
__global__ void xcatfill_k(const float* __restrict__ x, const float* __restrict__ inputs,
                           float* __restrict__ Xcat0, float* __restrict__ Xcat1){
  int idx = blockIdx.x*256 + threadIdx.x;  // < 256*1024
  int b = idx >> 10, c = idx & 1023;
  if (c < 512){
    Xcat0[(size_t)b*1536 + c] = x[(size_t)b*512 + c];
  } else {
    int r = c - 512;
    Xcat0[(size_t)b*1536 + c] = inputs[(size_t)1*131072 + b*512 + r];
    Xcat1[(size_t)b*1536 + c] = inputs[(size_t)3*131072 + b*512 + r];
  }
}

// ---------- LSTM gates ----------
__global__ void gate_k(const float* __restrict__ sums, const float* __restrict__ prev_c,
                       float* __restrict__ out_c, float* __restrict__ out_h,
                       float* __restrict__ hdst, int hstride){
  int idx = blockIdx.x*256 + threadIdx.x;  // < 131072
  int b = idx >> 9, r = idx & 511;
  const float* s = sums + (size_t)b*2048;
  float ig = 1.0f/(1.0f + __expf(-s[r]));
  float fg = 1.0f/(1.0f + __expf(-s[512+r]));
  float og = 1.0f/(1.0f + __expf(-s[1024+r]));
  float g  = fast_tanh(s[1536+r]);
  float c = fg*prev_c[idx] + ig*g;
  float h = og*fast_tanh(c);
  out_c[idx] = c;
  out_h[idx] = h;
  hdst[(size_t)b*hstride + r] = h;
}

// ---------- log_softmax over V=10000, one block per b ----------
__global__ void logsoftmax_k(const float* __restrict__ logits, float* __restrict__ out){
  int b = blockIdx.x, t = threadIdx.x;  // 256 threads
  __shared__ float red[4], red2[4];
  const float* p = logits + (size_t)b*VV;
  float mx = -3.4e38f;
  for (int i = t; i < VV; i += 256) mx = fmaxf(mx, p[i]);
  #pragma unroll
  for (int o = 1; o < 64; o <<= 1) mx = fmaxf(mx, __shfl_xor(mx, o, 64));
  if ((t & 63) == 0) red[t >> 6] = mx;
  __syncthreads();
  mx = fmaxf(fmaxf(red[0], red[1]), fmaxf(red[2], red[3]));
  float sum = 0.0f;
  for (int i = t; i < VV; i += 256) sum += __expf(p[i] - mx);
  #pragma unroll
  for (int o = 1; o < 64; o <<= 1) sum += __shfl_xor(sum, o, 64);
  if ((t & 63) == 0) red2[t >> 6] = sum;
  __syncthreads();
  sum = red2[0] + red2[1] + red2[2] + red2[3];
  float lse = mx + logf(sum);
  float* q = out + (size_t)b*VV;
  for (int i = t; i < VV; i += 256) q[i] = p[i] - lse;
}

extern "C" void kernel_launch(void* const* d_in, const int* in_sizes, int n_in,
                              void* d_out_, int out_size, void* d_ws, size_t ws_size,
                              hipStream_t stream){
  const float* x     = (const float*)d_in[0];
  const float* att   = (const float*)d_in[1];
  const float* inputs= (const float*)d_in[2];
  const float* Wa2a  = (const float*)d_in[3];
  const float* ba2a  = (const float*)d_in[4];
  const float* Wh2a  = (const float*)d_in[5];
  const float* bh2a  = (const float*)d_in[6];
  const float* wd2d  = (const float*)d_in[7];
  // d_in[8] = bd2d : scalar added uniformly before softmax -> softmax-invariant, unused
  const float* Wi2h  = (const float*)d_in[9];
  const float* bi2h  = (const float*)d_in[10];
  const float* Wh2h  = (const float*)d_in[11];
  const float* bh2h  = (const float*)d_in[12];
  const float* Wr2a  = (const float*)d_in[13];
  const float* br2a  = (const float*)d_in[14];
  const float* Wproj = (const float*)d_in[15];
  const float* bproj = (const float*)d_in[16];
  float* d_out = (float*)d_out_;

  char* wsp = (char*)d_ws;
  auto alloc = [&](size_t bytes)->char*{
    char* p = wsp;
    wsp += (bytes + 255) & ~(size_t)255;
    return p;
  };
  __bf16* Wa2a_bf  = (__bf16*)alloc((size_t)AA*RR*2);
  __bf16* Wh2a_bf  = (__bf16*)alloc((size_t)AA*RR*2);
  __bf16* Wcat_bf  = (__bf16*)alloc((size_t)2048*1536*2);
  __bf16* Wproj_bf = (__bf16*)alloc((size_t)VV*RR*2);
  float* ba_pad = (float*)alloc(208*4);
  float* wd_pad = (float*)alloc(208*4);
  float* bcat   = (float*)alloc(2048*4);
  float* att_h  = (float*)alloc((size_t)2*MATT*4);
  float* score  = (float*)alloc((size_t)2*MATT*4);
  float* wsm    = (float*)alloc((size_t)2*MATT*4);
  float* Xcat0  = (float*)alloc((size_t)BB*1536*4);
  float* Xcat1  = (float*)alloc((size_t)BB*1536*4);
  float* sums   = (float*)alloc((size_t)BB*2048*4);
  float* h1buf  = (float*)alloc((size_t)BB*RR*4);
  float* logits = (float*)alloc((size_t)BB*VV*4);

  // weight prep
  cvt_k<<<(AA*RR+255)/256, 256, 0, stream>>>(Wa2a, Wa2a_bf, AA*RR);
  cvt_k<<<(AA*RR+255)/256, 256, 0, stream>>>(Wh2a, Wh2a_bf, AA*RR);
  cvt_k<<<(VV*RR+255)/256, 256, 0, stream>>>(Wproj, Wproj_bf, VV*RR);
  wcat_k<<<(2048*1536)/256, 256, 0, stream>>>(Wi2h, Wh2h, Wr2a, Wcat_bf);
  build_small_k<<<10, 256, 0, stream>>>(ba2a, wd2d, bi2h, bh2h, br2a, ba_pad, wd_pad, bcat);

  // attention (layer-invariant except att_h, and att_h depends only on fixed inputs)
  gemm_bf16_k<<<dim3(4,4), 256, 0, stream>>>(inputs + 1*131072, Wh2a_bf, bh2a, att_h,        256, AA, 512);
  gemm_bf16_k<<<dim3(4,4), 256, 0, stream>>>(inputs + 3*131072, Wh2a_bf, bh2a, att_h + MATT, 256, AA, 512);
  att_score_kernel<<<MATT/128, 256, 0, stream>>>(att, Wa2a_bf, ba_pad, wd_pad, att_h, score);
  softmax196_k<<<512, 64, 0, stream>>>(score, wsm);
  attres_k<<<256, 512, 0, stream>>>(att, wsm, Xcat0, Xcat1);
  xcatfill_k<<<1024, 256, 0, stream>>>(x, inputs, Xcat0, Xcat1);

  // layer 0
  gemm_bf16_k<<<dim3(32,4), 256, 0, stream>>>(Xcat0, Wcat_bf, bcat, sums, 256, 2048, 1536);
  gate_k<<<512, 256, 0, stream>>>(sums, inputs, d_out, d_out + 131072, Xcat1, 1536);
  // layer 1
  gemm_bf16_k<<<dim3(32,4), 256, 0, stream>>>(Xcat1, Wcat_bf, bcat, sums, 256, 2048, 1536);
  gate_k<<<512, 256, 0, stream>>>(sums, inputs + 2*131072, d_out + 2*131072, d_out + 3*131072, h1buf, 512);

  // projection + log_softmax
  gemm_bf16_k<<<dim3(157,4), 256, 0, stream>>>(h1buf, Wproj_bf, bproj, logits, 256, VV, 512);
  logsoftmax_k<<<256, 256, 0, stream>>>(logits, d_out + 4*131072);
}

// Round 3
// 237.295 us; speedup vs baseline: 1.2143x; 1.2143x over previous
//
#include <hip/hip_runtime.h>
#include <hip/hip_bf16.h>
#include <cstdint>
#include <cstddef>

#define BB 256
#define RR 512
#define AA 196
#define VV 10000
#define MATT (BB*AA)   // 50176
#define NT13 13        // 13*16 = 208 padded attention cols

typedef float f32x4 __attribute__((ext_vector_type(4)));
typedef __bf16 bf16x8 __attribute__((ext_vector_type(8)));
typedef __bf16 bf16x4 __attribute__((ext_vector_type(4)));

#define MFMA16(a,b,c) __builtin_amdgcn_mfma_f32_16x16x32_bf16(a,b,c,0,0,0)

__device__ __forceinline__ float fast_tanh(float x){
  float ax = fabsf(x);
  float e = __expf(-2.0f*ax);
  float t = __fdividef(1.0f - e, 1.0f + e);
  return x < 0.0f ? -t : t;
}

__device__ __forceinline__ bf16x8 ldfrag_f32(const float* p){
  const float4* q = (const float4*)p;
  float4 f0 = q[0];
  float4 f1 = q[1];
  bf16x8 r;
  r[0]=(__bf16)f0.x; r[1]=(__bf16)f0.y; r[2]=(__bf16)f0.z; r[3]=(__bf16)f0.w;
  r[4]=(__bf16)f1.x; r[5]=(__bf16)f1.y; r[6]=(__bf16)f1.z; r[7]=(__bf16)f1.w;
  return r;
}
__device__ __forceinline__ bf16x8 ldfrag_bf(const __bf16* p){
  return *(const bf16x8*)p;
}

// async global -> LDS, 16B per lane (wave-uniform LDS base + lane*16)
__device__ __forceinline__ void gload16(const void* gsrc, void* ldsdst){
  __builtin_amdgcn_global_load_lds(
      (const __attribute__((address_space(1))) unsigned int*)gsrc,
      (__attribute__((address_space(3))) unsigned int*)ldsdst,
      16, 0, 0);
}

// ---------- weight prep ----------
__global__ void cvt_k(const float* __restrict__ src, __bf16* __restrict__ dst, int n){
  int i = blockIdx.x*256 + threadIdx.x;
  if (i < n) dst[i] = (__bf16)src[i];
}

// vectorized f32 -> bf16, n4 = n/4
__global__ void cvt4_k(const float* __restrict__ src, __bf16* __restrict__ dst, int n4){
  int i = blockIdx.x*256 + threadIdx.x;
  if (i < n4){
    float4 v = ((const float4*)src)[i];
    bf16x4 o;
    o[0]=(__bf16)v.x; o[1]=(__bf16)v.y; o[2]=(__bf16)v.z; o[3]=(__bf16)v.w;
    ((bf16x4*)dst)[i] = o;
  }
}

// Wa2a -> [208][512] bf16, rows 196..207 zero
__global__ void cvt_pad_k(const float* __restrict__ src, __bf16* __restrict__ dst){
  int i = blockIdx.x*256 + threadIdx.x;   // < 208*512
  int row = i >> 9, k = i & 511;
  dst[i] = (__bf16)((row < AA) ? src[row*512 + k] : 0.0f);
}

__global__ void wcat2_k(const float* __restrict__ Wi2h, const float* __restrict__ Wh2h,
                        const float* __restrict__ Wr2a, __bf16* __restrict__ Wcat){
  int k = blockIdx.x*256 + threadIdx.x;   // 0..1535
  int n = blockIdx.y;                     // 0..2047
  float v;
  if (k < 512)       v = Wi2h[n*512 + k];
  else if (k < 1024) v = Wh2h[n*512 + (k-512)];
  else               v = Wr2a[n*512 + (k-1024)];
  Wcat[(size_t)n*1536 + k] = (__bf16)v;
}

__global__ void build_small_k(const float* __restrict__ ba2a, const float* __restrict__ wd2d,
                              const float* __restrict__ bi2h, const float* __restrict__ bh2h,
                              const float* __restrict__ br2a,
                              float* __restrict__ ba_pad, float* __restrict__ wd_pad,
                              float* __restrict__ bcat){
  int i = blockIdx.x*256 + threadIdx.x;
  if (i < 2048){
    bcat[i] = bi2h[i] + bh2h[i] + br2a[i];
  } else if (i < 2048+208){
    int j = i - 2048; ba_pad[j] = (j < AA) ? ba2a[j] : 0.0f;
  } else if (i < 2048+416){
    int j = i - 2256; wd_pad[j] = (j < AA) ? wd2d[j] : 0.0f;
  }
}

// ---------- GEMM: C[m][n] = sum_k A[m][k]*W[n][k] + bias[n], BM=32 BN=64 ----------
// 256 thr = 4 waves, wave w owns cols [bx*64 + w*16, +16), rows [by*32, +32)
__global__ __launch_bounds__(256,4) void gemm2_k(
    const float* __restrict__ A, const __bf16* __restrict__ Bw,
    const float* __restrict__ bias, float* __restrict__ C,
    int M, int N, int K)
{
  const int l = threadIdx.x & 63;
  const int w = threadIdx.x >> 6;
  const int l15 = l & 15;
  const int kg = (l >> 4) * 8;
  const int mrow = blockIdx.y*32;
  const int ncol = blockIdx.x*64 + w*16;
  int c0 = ncol + l15;
  int c0c = c0 < N ? c0 : N-1;
  const float*  pa0 = A  + (size_t)(mrow + l15)*K + kg;
  const float*  pa1 = pa0 + (size_t)16*K;
  const __bf16* pb0 = Bw + (size_t)c0c*K + kg;

  f32x4 acc[2] = {};
  #pragma unroll 4
  for (int k = 0; k < K; k += 32){
    bf16x8 a0 = ldfrag_f32(pa0 + k);
    bf16x8 a1 = ldfrag_f32(pa1 + k);
    bf16x8 b0 = ldfrag_bf(pb0 + k);
    acc[0] = MFMA16(a0, b0, acc[0]);
    acc[1] = MFMA16(a1, b0, acc[1]);
  }
  const int rbase = (l >> 4) * 4;
  #pragma unroll
  for (int mt = 0; mt < 2; mt++)
  #pragma unroll
  for (int r = 0; r < 4; r++){
    int row = mrow + mt*16 + rbase + r;
    int col = ncol + l15;
    if (col < N) C[(size_t)row*N + col] = acc[mt][r] + bias[col];
  }
}

// ---------- fused attention score, LDS-staged ----------
// Block: 64 att rows x 208 cols, K=512 in 8 chunks of 64.
// A chunk: f32 [64][64] XOR-swizzled; B chunk: bf16 [208][64] XOR-swizzled.
// Both staged with global_load_lds (linear LDS dest, pre-swizzled global source).
__global__ __launch_bounds__(256,3) void att_score2_k(
    const float* __restrict__ att, const __bf16* __restrict__ Wa2a_p,
    const float* __restrict__ ba_pad, const float* __restrict__ wd_pad,
    const float* __restrict__ att_h, float* __restrict__ score)
{
  __shared__ float  Ash[64*64];     // 16 KB
  __shared__ __bf16 Bsh[208*64];    // 26 KB
  const int t = threadIdx.x;
  const int l = t & 63;
  const int w = t >> 6;
  const int l15 = l & 15;
  const int g  = l >> 4;
  const int rowbase = blockIdx.x * 64;

  // ---- staging descriptors (constant across chunks except +kc) ----
  // A: 1024 slots of 16B (4 f32). slot -> (row = slot>>4, js = slot&15),
  //    LDS linear; source column pre-swizzled: k = (js ^ (row&7))*4
  const float* asrc[4]; int aslot[4];
  #pragma unroll
  for (int i = 0; i < 4; i++){
    int id = i*4 + w;
    int slotbase = id*64;
    int slot = slotbase + l;
    int row = slot >> 4;
    int js  = slot & 15;
    aslot[i] = slotbase*4;
    asrc[i]  = att + (size_t)(rowbase+row)*RR + ((js ^ (row&7))<<2);
  }
  // B: 1664 slots of 16B (8 bf16). slot -> (row = slot>>3, j = slot&7),
  //    source k = (j ^ (row&7))*8
  const __bf16* bsrc[7]; int bslot[7];
  #pragma unroll
  for (int i = 0; i < 7; i++){
    int id = i*4 + w;
    int idc = id < 26 ? id : 25;
    int slotbase = idc*64;
    int slot = slotbase + l;
    int row = slot >> 3;
    int j   = slot & 7;
    bslot[i] = slotbase*8;
    bsrc[i]  = Wa2a_p + (size_t)row*RR + ((j ^ (row&7))<<3);
  }

  const int arow = w*16 + l15;          // this wave's A row for its M-frag
  const int rho  = l15 & 7;             // arow&7 == col&7 == l15&7

  f32x4 acc[NT13] = {};

  for (int c = 0; c < 8; c++){
    const int kc = c*64;
    __syncthreads();                    // previous chunk's reads done
    #pragma unroll
    for (int i = 0; i < 4; i++)
      gload16(asrc[i] + kc, Ash + aslot[i]);
    #pragma unroll
    for (int i = 0; i < 7; i++)
      if (i*4 + w < 26) gload16(bsrc[i] + kc, Bsh + bslot[i]);
    __syncthreads();                    // staged data visible (vmcnt drained)

    #pragma unroll
    for (int s = 0; s < 2; s++){
      // A fragment: 8 f32 = two swizzled 16B slots, convert to bf16
      const float4 fa0 = *(const float4*)&Ash[arow*64 + (((s*8 + 2*g    ) ^ rho)<<2)];
      const float4 fa1 = *(const float4*)&Ash[arow*64 + (((s*8 + 2*g + 1) ^ rho)<<2)];
      bf16x8 a;
      a[0]=(__bf16)fa0.x; a[1]=(__bf16)fa0.y; a[2]=(__bf16)fa0.z; a[3]=(__bf16)fa0.w;
      a[4]=(__bf16)fa1.x; a[5]=(__bf16)fa1.y; a[6]=(__bf16)fa1.z; a[7]=(__bf16)fa1.w;
      const int sw = ((s*4 + g) ^ rho) << 3;
      #pragma unroll
      for (int nt = 0; nt < NT13; nt++){
        bf16x8 b = *(const bf16x8*)&Bsh[nt*1024 + l15*64 + sw];
        acc[nt] = MFMA16(a, b, acc[nt]);
      }
    }
  }

  // ---- fused epilogue: tanh(acc + ba + att_h) . wd2d, both layers ----
  float wdv[NT13], bav[NT13];
  #pragma unroll
  for (int nt = 0; nt < NT13; nt++){
    int col = nt*16 + l15;
    wdv[nt] = wd_pad[col];
    bav[nt] = ba_pad[col];
  }
  #pragma unroll
  for (int r = 0; r < 4; r++){
    int row = rowbase + w*16 + g*4 + r;
    float ah0 = att_h[row];
    float ah1 = att_h[MATT + row];
    float s0 = 0.0f, s1 = 0.0f;
    #pragma unroll
    for (int nt = 0; nt < NT13; nt++){
      float v = acc[nt][r] + bav[nt];
      s0 += fast_tanh(v + ah0) * wdv[nt];
      s1 += fast_tanh(v + ah1) * wdv[nt];
    }
    #pragma unroll
    for (int o = 1; o < 16; o <<= 1){
      s0 += __shfl_xor(s0, o, 16);
      s1 += __shfl_xor(s1, o, 16);
    }
    if (l15 == 0){
      score[row] = s0;
      score[MATT + row] = s1;
    }
  }
}

// ---------- softmax over 196 positions, one wave per (layer,b) ----------
__global__ void softmax196_k(const float* __restrict__ score, float* __restrict__ wsm){
  int lb = blockIdx.x;          // l*256 + b
  int t = threadIdx.x;          // 64
  const float* s = score + (size_t)lb*AA;
  float v0 = (t      < AA) ? s[t]       : -3.4e38f;
  float v1 = (t+64   < AA) ? s[t+64]    : -3.4e38f;
  float v2 = (t+128  < AA) ? s[t+128]   : -3.4e38f;
  float v3 = (t+192  < AA) ? s[t+192]   : -3.4e38f;
  float mx = fmaxf(fmaxf(v0,v1), fmaxf(v2,v3));
  #pragma unroll
  for (int o = 1; o < 64; o <<= 1) mx = fmaxf(mx, __shfl_xor(mx, o, 64));
  float e0 = (t      < AA) ? __expf(v0 - mx) : 0.0f;
  float e1 = (t+64   < AA) ? __expf(v1 - mx) : 0.0f;
  float e2 = (t+128  < AA) ? __expf(v2 - mx) : 0.0f;
  float e3 = (t+192  < AA) ? __expf(v3 - mx) : 0.0f;
  float sum = e0+e1+e2+e3;
  #pragma unroll
  for (int o = 1; o < 64; o <<= 1) sum += __shfl_xor(sum, o, 64);
  float inv = 1.0f / sum;
  float* o_ = wsm + (size_t)lb*AA;
  if (t      < AA) o_[t]     = e0*inv;
  if (t+64   < AA) o_[t+64]  = e1*inv;
  if (t+128  < AA) o_[t+128] = e2*inv;
  if (t+192  < AA) o_[t+192] = e3*inv;
}

// ---------- att_res for both layers, writes straight into Xcat slots ----------
__global__ void attres_k(const float* __restrict__ att, const float* __restrict__ wsm,
                         float* __restrict__ Xcat0, float* __restrict__ Xcat1){
  int b = blockIdx.x, t = threadIdx.x;  // 512 threads, t = r
  __shared__ float w0[AA], w1[AA];
  if (t < AA) w0[t] = wsm[(size_t)b*AA + t];
  int t2 = t - 256;
  if (t2 >= 0 && t2 < AA) w1[t2] = wsm[(size_t)(256+b)*AA + t2];
  __syncthreads();
  const float* ap = att + (size_t)b*AA*RR + t;
  float s00=0, s01=0, s10=0, s11=0;
  #pragma unroll 2
  for (int i = 0; i < AA; i += 2){
    float x0 = ap[(size_t)i*RR];
    float x1 = ap[(size_t)(i+1)*RR];
    s00 += w0[i]*x0;   s10 += w1[i]*x0;
    s01 += w0[i+1]*x1; s11 += w1[i+1]*x1;
  }
  Xcat0[(size_t)b*1536 + 1024 + t] = s00 + s01;
  Xcat1[(size_t)b*1536 + 1024 + t] = s10 + s11;
}

// ---------- fill Xcat cur/prev_h slots ----------
__global__ void xcatfill_k(const float* __restrict__ x, const float* __restrict__ inputs,
                           float* __restrict__ Xcat0, float* __restrict__ Xcat1){
  int idx = blockIdx.x*256 + threadIdx.x;  // < 256*1024
  int b = idx >> 10, c = idx & 1023;
  if (c < 512){
    Xcat0[(size_t)b*1536 + c] = x[(size_t)b*512 + c];
  } else {
    int r = c - 512;
    Xcat0[(size_t)b*1536 + c] = inputs[(size_t)1*131072 + b*512 + r];
    Xcat1[(size_t)b*1536 + c] = inputs[(size_t)3*131072 + b*512 + r];
  }
}

// ---------- LSTM gates ----------
__global__ void gate_k(const float* __restrict__ sums, const float* __restrict__ prev_c,
                       float* __restrict__ out_c, float* __restrict__ out_h,
                       float* __restrict__ hdst, int hstride){
  int idx = blockIdx.x*256 + threadIdx.x;  // < 131072
  int b = idx >> 9, r = idx & 511;
  const float* s = sums + (size_t)b*2048;
  float ig = 1.0f/(1.0f + __expf(-s[r]));
  float fg = 1.0f/(1.0f + __expf(-s[512+r]));
  float og = 1.0f/(1.0f + __expf(-s[1024+r]));
  float g  = fast_tanh(s[1536+r]);
  float c = fg*prev_c[idx] + ig*g;
  float h = og*fast_tanh(c);
  out_c[idx] = c;
  out_h[idx] = h;
  hdst[(size_t)b*hstride + r] = h;
}

// ---------- log_softmax over V=10000, one block per b ----------
__global__ void logsoftmax_k(const float* __restrict__ logits, float* __restrict__ out){
  int b = blockIdx.x, t = threadIdx.x;  // 256 threads
  __shared__ float red[4], red2[4];
  const float* p = logits + (size_t)b*VV;
  float mx = -3.4e38f;
  for (int i = t; i < VV; i += 256) mx = fmaxf(mx, p[i]);
  #pragma unroll
  for (int o = 1; o < 64; o <<= 1) mx = fmaxf(mx, __shfl_xor(mx, o, 64));
  if ((t & 63) == 0) red[t >> 6] = mx;
  __syncthreads();
  mx = fmaxf(fmaxf(red[0], red[1]), fmaxf(red[2], red[3]));
  float sum = 0.0f;
  for (int i = t; i < VV; i += 256) sum += __expf(p[i] - mx);
  #pragma unroll
  for (int o = 1; o < 64; o <<= 1) sum += __shfl_xor(sum, o, 64);
  if ((t & 63) == 0) red2[t >> 6] = sum;
  __syncthreads();
  sum = red2[0] + red2[1] + red2[2] + red2[3];
  float lse = mx + logf(sum);
  float* q = out + (size_t)b*VV;
  for (int i = t; i < VV; i += 256) q[i] = p[i] - lse;
}

extern "C" void kernel_launch(void* const* d_in, const int* in_sizes, int n_in,
                              void* d_out_, int out_size, void* d_ws, size_t ws_size,
                              hipStream_t stream){
  const float* x     = (const float*)d_in[0];
  const float* att   = (const float*)d_in[1];
  const float* inputs= (const float*)d_in[2];
  const float* Wa2a  = (const float*)d_in[3];
  const float* ba2a  = (const float*)d_in[4];
  const float* Wh2a  = (const float*)d_in[5];
  const float* bh2a  = (const float*)d_in[6];
  const float* wd2d  = (const float*)d_in[7];
  // d_in[8] = bd2d : uniform pre-softmax scalar -> softmax-invariant, unused
  const float* Wi2h  = (const float*)d_in[9];
  const float* bi2h  = (const float*)d_in[10];
  const float* Wh2h  = (const float*)d_in[11];
  const float* bh2h  = (const float*)d_in[12];
  const float* Wr2a  = (const float*)d_in[13];
  const float* br2a  = (const float*)d_in[14];
  const float* Wproj = (const float*)d_in[15];
  const float* bproj = (const float*)d_in[16];
  float* d_out = (float*)d_out_;

  char* wsp = (char*)d_ws;
  auto alloc = [&](size_t bytes)->char*{
    char* p = wsp;
    wsp += (bytes + 255) & ~(size_t)255;
    return p;
  };
  __bf16* Wa2a_p   = (__bf16*)alloc((size_t)208*RR*2);   // zero-padded rows
  __bf16* Wh2a_bf  = (__bf16*)alloc((size_t)AA*RR*2);
  __bf16* Wcat_bf  = (__bf16*)alloc((size_t)2048*1536*2);
  __bf16* Wproj_bf = (__bf16*)alloc((size_t)VV*RR*2);
  float* ba_pad = (float*)alloc(208*4);
  float* wd_pad = (float*)alloc(208*4);
  float* bcat   = (float*)alloc(2048*4);
  float* att_h  = (float*)alloc((size_t)2*MATT*4);
  float* score  = (float*)alloc((size_t)2*MATT*4);
  float* wsm    = (float*)alloc((size_t)2*MATT*4);
  float* Xcat0  = (float*)alloc((size_t)BB*1536*4);
  float* Xcat1  = (float*)alloc((size_t)BB*1536*4);
  float* sums   = (float*)alloc((size_t)BB*2048*4);
  float* h1buf  = (float*)alloc((size_t)BB*RR*4);
  float* logits = (float*)alloc((size_t)BB*VV*4);

  // weight prep
  cvt_pad_k<<<(208*RR)/256, 256, 0, stream>>>(Wa2a, Wa2a_p);
  cvt_k<<<(AA*RR+255)/256, 256, 0, stream>>>(Wh2a, Wh2a_bf, AA*RR);
  cvt4_k<<<(VV*RR/4+255)/256, 256, 0, stream>>>(Wproj, Wproj_bf, VV*RR/4);
  wcat2_k<<<dim3(6,2048), 256, 0, stream>>>(Wi2h, Wh2h, Wr2a, Wcat_bf);
  build_small_k<<<10, 256, 0, stream>>>(ba2a, wd2d, bi2h, bh2h, br2a, ba_pad, wd_pad, bcat);

  // attention precompute (att_h depends only on fixed inputs, both layers)
  gemm2_k<<<dim3(4,8), 256, 0, stream>>>(inputs + 1*131072, Wh2a_bf, bh2a, att_h,        256, AA, 512);
  gemm2_k<<<dim3(4,8), 256, 0, stream>>>(inputs + 3*131072, Wh2a_bf, bh2a, att_h + MATT, 256, AA, 512);
  att_score2_k<<<784, 256, 0, stream>>>(att, Wa2a_p, ba_pad, wd_pad, att_h, score);
  softmax196_k<<<512, 64, 0, stream>>>(score, wsm);
  attres_k<<<256, 512, 0, stream>>>(att, wsm, Xcat0, Xcat1);
  xcatfill_k<<<1024, 256, 0, stream>>>(x, inputs, Xcat0, Xcat1);

  // layer 0
  gemm2_k<<<dim3(32,8), 256, 0, stream>>>(Xcat0, Wcat_bf, bcat, sums, 256, 2048, 1536);
  gate_k<<<512, 256, 0, stream>>>(sums, inputs, d_out, d_out + 131072, Xcat1, 1536);
  // layer 1
  gemm2_k<<<dim3(32,8), 256, 0, stream>>>(Xcat1, Wcat_bf, bcat, sums, 256, 2048, 1536);
  gate_k<<<512, 256, 0, stream>>>(sums, inputs + 2*131072, d_out + 2*131072, d_out + 3*131072, h1buf, 512);

  // projection + log_softmax
  gemm2_k<<<dim3(157,8), 256, 0, stream>>>(h1buf, Wproj_bf, bproj, logits, 256, VV, 512);
  logsoftmax_k<<<256, 256, 0, stream>>>(logits, d_out + 4*131072);
}